// Round 16
// baseline (319.406 us; speedup 1.0000x reference)
//
#include <hip/hip_runtime.h>
#include <hip/hip_bf16.h>
#include <hip/hip_cooperative_groups.h>

namespace cg = cooperative_groups;

using bf16 = __hip_bfloat16;
typedef __attribute__((ext_vector_type(4))) float f32x4;
typedef __attribute__((ext_vector_type(2))) float f32x2;
typedef __attribute__((ext_vector_type(8))) __bf16 bf16x8;
typedef __attribute__((ext_vector_type(4))) __bf16 bf16x4;

#define CIN 256
#define COUT 256
#define HW 4096
#define NB 4
#define NTOT 16384   // NB*HW
#define KDIM 2304    // CIN*9

// ---------- 1. merged pre-pass ----------
// blocks    0..2047: transpose x NCHW f32 -> xt NHWC bf16 (64c x 32hw tiles)
// blocks 2048..4351: w[o][c][p] f32 -> A[o][p*256+c] bf16
// blocks 4352..4513: wof[oc][c][p] -> wt[c][p][oc]
// block  4514      : zero gsum/gsq (256 floats)
__global__ __launch_bounds__(256) void k_pre(const float* __restrict__ x,
                                             const float* __restrict__ w,
                                             const float* __restrict__ wof,
                                             bf16* __restrict__ xt,
                                             bf16* __restrict__ A,
                                             float* __restrict__ wt,
                                             float* __restrict__ gstats) {
  int bid = blockIdx.x;
  int tid = threadIdx.x;
  if (bid < 2048) {
    __shared__ float t[64][33];
    int ct = bid & 3;
    int hwt = (bid >> 2) & 127;
    int b = bid >> 9;
    int c0 = ct * 64, hw0 = hwt * 32;
    const float* xb = x + (size_t)b * CIN * HW;
    int cc = tid >> 5, ww = tid & 31;
#pragma unroll
    for (int pass = 0; pass < 8; ++pass)
      t[cc + pass * 8][ww] = xb[(size_t)(c0 + cc + pass * 8) * HW + hw0 + ww];
    __syncthreads();
    int hwl = tid >> 3, ce = (tid & 7) * 8;
    bf16x8 v;
#pragma unroll
    for (int e = 0; e < 8; ++e) v[e] = (__bf16)t[ce + e][hwl];
    *(bf16x8*)(xt + ((size_t)b * HW + hw0 + hwl) * CIN + c0 + ce) = v;
  } else if (bid < 4352) {
    int i = (bid - 2048) * 256 + tid;  // o*2304 + p*256 + c
    int o = i / KDIM, r = i % KDIM;
    int p = r >> 8, c = r & 255;
    A[i] = __float2bfloat16(w[((size_t)o * 256 + c) * 9 + p]);
  } else if (bid < 4514) {
    int i = (bid - 4352) * 256 + tid;  // (c*9+p)*18 + oc
    if (i < 18 * CIN * 9) {
      int oc = i % 18;
      int cp = i / 18;
      int c = cp / 9, p = cp % 9;
      wt[i] = wof[((size_t)oc * CIN + c) * 9 + p];
    }
  } else {
    gstats[tid] = 0.f;
  }
}

// ---------- 2. offset conv partials: LDS-tiled, channel-chunked ----------
__global__ __launch_bounds__(256) void k_convoff2(const float* __restrict__ x,
                                                  const float* __restrict__ wt,
                                                  float* __restrict__ part) {
  __shared__ float lds[8][6][68];
  int bid = blockIdx.x;
  int chunk = bid & 7;
  int rt = (bid >> 3) & 15;
  int b = bid >> 7;
  int tid = threadIdx.x;
  int wq = tid & 63, r = tid >> 6;
  int h0 = rt * 4;
  int c0 = chunk * 32;

  if (tid < 96) {
    int cl = tid / 12, rem = tid % 12;
    lds[cl][rem >> 1][(rem & 1) ? 66 : 1] = 0.f;
  }

  float acc[18];
#pragma unroll
  for (int o = 0; o < 18; ++o) acc[o] = 0.f;

  int ch = tid >> 5, l32 = tid & 31;
  const float* xb = x + (size_t)b * CIN * HW;

  for (int cs = 0; cs < 32; cs += 8) {
    __syncthreads();
    const float* xp = xb + (size_t)(c0 + cs + ch) * HW;
#pragma unroll
    for (int r6 = 0; r6 < 6; ++r6) {
      int hh = h0 - 1 + r6;
      f32x2 v = {0.f, 0.f};
      if ((unsigned)hh < 64u) v = *(const f32x2*)(xp + hh * 64 + l32 * 2);
      *(f32x2*)&lds[ch][r6][2 + l32 * 2] = v;
    }
    __syncthreads();
#pragma unroll
    for (int cl = 0; cl < 8; ++cl) {
      int c = c0 + cs + cl;
      const float* wc = wt + (size_t)c * 9 * 18;
      float xv[9];
#pragma unroll
      for (int ky = 0; ky < 3; ++ky)
#pragma unroll
        for (int kx = 0; kx < 3; ++kx)
          xv[ky * 3 + kx] = lds[cl][r + ky][1 + wq + kx];
#pragma unroll
      for (int p = 0; p < 9; ++p)
#pragma unroll
        for (int o = 0; o < 18; ++o)
          acc[o] = fmaf(xv[p], wc[p * 18 + o], acc[o]);
    }
  }

  float* pp = part + (size_t)chunk * (NB * 18 * HW) + (size_t)b * 18 * HW +
              (h0 + r) * 64 + wq;
#pragma unroll
  for (int o = 0; o < 18; ++o) pp[(size_t)o * HW] = acc[o];
}

// ---------- 3. reduce channel-chunk partials + bias -> off[b][18][hw] ----------
__global__ __launch_bounds__(256) void k_offreduce(const float* __restrict__ part,
                                                   const float* __restrict__ boff,
                                                   float* __restrict__ off) {
  int i = blockIdx.x * 256 + threadIdx.x;
  int e0 = i * 4;
  int oc = (e0 >> 12) % 18;
  float bo = boff[oc];
  f32x4 s = {bo, bo, bo, bo};
#pragma unroll
  for (int c = 0; c < 8; ++c) s += *(const f32x4*)(part + (size_t)c * (NB * 18 * HW) + e0);
  *(f32x4*)(off + e0) = s;
}

// ---------- 4. bilinear gather (bf16 corners) -> colsT[n][p*256+c] ----------
__global__ __launch_bounds__(256) void k_gather(const bf16* __restrict__ xt,
                                                const float* __restrict__ off,
                                                bf16* __restrict__ colsT) {
  int tid = threadIdx.x;
  int wv = tid >> 6, l = tid & 63;
  int n = blockIdx.x * 4 + wv;
  int hw = n & 4095;
  int b = n >> 12;
  int h = hw >> 6, wq = hw & 63;
  const bf16* xtb = xt + (size_t)b * HW * CIN + l * 4;
  const float* offb = off + (size_t)b * 18 * HW + hw;
  bf16* outp = colsT + (size_t)n * KDIM + l * 4;
#pragma unroll
  for (int p = 0; p < 9; ++p) {
    float dy = offb[(size_t)(2 * p) * HW];
    float dx = offb[(size_t)(2 * p + 1) * HW];
    float ysf = (float)(h - 1 + p / 3) + dy;
    float xsf = (float)(wq - 1 + p % 3) + dx;
    float y0f = floorf(ysf), x0f = floorf(xsf);
    float wy1 = ysf - y0f, wx1 = xsf - x0f;
    float wy0 = 1.f - wy1, wx0 = 1.f - wx1;
    int y0 = (int)y0f, x0 = (int)x0f;
    int y1 = y0 + 1, x1 = x0 + 1;
    float w00 = wy0 * wx0, w01 = wy0 * wx1, w10 = wy1 * wx0, w11 = wy1 * wx1;
    bool vy0 = (unsigned)y0 < 64u, vy1 = (unsigned)y1 < 64u;
    bool vx0 = (unsigned)x0 < 64u, vx1 = (unsigned)x1 < 64u;
    w00 = (vy0 && vx0) ? w00 : 0.f;
    w01 = (vy0 && vx1) ? w01 : 0.f;
    w10 = (vy1 && vx0) ? w10 : 0.f;
    w11 = (vy1 && vx1) ? w11 : 0.f;
    int y0c = min(max(y0, 0), 63), y1c = min(max(y1, 0), 63);
    int x0c = min(max(x0, 0), 63), x1c = min(max(x1, 0), 63);
    bf16x4 c00 = *(const bf16x4*)(xtb + (size_t)(y0c * 64 + x0c) * CIN);
    bf16x4 c01 = *(const bf16x4*)(xtb + (size_t)(y0c * 64 + x1c) * CIN);
    bf16x4 c10 = *(const bf16x4*)(xtb + (size_t)(y1c * 64 + x0c) * CIN);
    bf16x4 c11 = *(const bf16x4*)(xtb + (size_t)(y1c * 64 + x1c) * CIN);
    bf16x4 o;
#pragma unroll
    for (int k = 0; k < 4; ++k) {
      float v = w00 * (float)c00[k] + w01 * (float)c01[k] +
                w10 * (float)c10[k] + w11 * (float)c11[k];
      o[k] = (__bf16)v;
    }
    *(bf16x4*)(outp + p * 256) = o;
  }
}

// ---------- 5. split-K GEMM: BM=256, BN=64, K halved; 512 blocks (2/CU) ----------
__global__ __launch_bounds__(256) void k_gemm(const bf16* __restrict__ A,
                                              const bf16* __restrict__ Bt,
                                              const float* __restrict__ bias,
                                              bf16* __restrict__ Y0,
                                              bf16* __restrict__ Y1) {
  __shared__ bf16 As[2][256 * 64];  // 32 KB each
  __shared__ bf16 Bs[2][64 * 64];   //  8 KB each -> 80 KB total
  int bid = blockIdx.x;
  // bijective XCD swizzle over 512 blocks; pair (n-tile, khalf) stays on XCD
  int swz = (bid & 7) * 64 + (bid >> 3);
  int n0 = (swz >> 1) * 64;
  int khalf = swz & 1;
  int tid = threadIdx.x;
  int lane = tid & 63;
  int wave = tid >> 6;
  int wr = wave * 64;               // per-wave 64x64 output tile
  f32x4 acc[4][4];
#pragma unroll
  for (int i = 0; i < 4; ++i)
#pragma unroll
    for (int j = 0; j < 4; ++j) acc[i][j] = (f32x4){0.f, 0.f, 0.f, 0.f};

  int srow = tid >> 3;                              // 0..31
  int skdst = (tid & 7) * 8;                        // linear dest k-chunk
  int sksrc = ((tid & 7) ^ ((tid >> 3) & 7)) * 8;   // pre-swizzled source (T2)
  int kbase = khalf * 18;                           // K-step offset
  auto stage = [&](int buf, int kt) {               // 10 loads/thread
    int k0 = (kbase + kt) * 64;
#pragma unroll
    for (int ps = 0; ps < 8; ++ps) {
      int r = srow + ps * 32;
      __builtin_amdgcn_global_load_lds(
          (const __attribute__((address_space(1))) void*)(A + (size_t)r * KDIM + k0 + sksrc),
          (__attribute__((address_space(3))) void*)(&As[buf][r * 64 + skdst]), 16, 0, 0);
    }
#pragma unroll
    for (int ps = 0; ps < 2; ++ps) {
      int r = srow + ps * 32;
      __builtin_amdgcn_global_load_lds(
          (const __attribute__((address_space(1))) void*)(Bt + (size_t)(n0 + r) * KDIM + k0 + sksrc),
          (__attribute__((address_space(3))) void*)(&Bs[buf][r * 64 + skdst]), 16, 0, 0);
    }
  };

  stage(0, 0);
  int rl = lane & 15;
  int kb = (lane >> 4) * 8;
  int xorv = (rl & 7) * 8;  // read-side XOR (row&7)*8 elements; row&7 == rl&7
  for (int kt = 0; kt < 18; ++kt) {
    __syncthreads();  // drains vmcnt -> buf[kt&1] ready; all prev reads done
    if (kt + 1 < 18) stage((kt + 1) & 1, kt + 1);
    const bf16* as = As[kt & 1];
    const bf16* bs = Bs[kt & 1];
#pragma unroll
    for (int kh = 0; kh < 2; ++kh) {
      int kc = (kh * 32 + kb) ^ xorv;
      bf16x8 af[4], bfr[4];
#pragma unroll
      for (int i = 0; i < 4; ++i)
        af[i] = *(const bf16x8*)(as + (wr + i * 16 + rl) * 64 + kc);
#pragma unroll
      for (int j = 0; j < 4; ++j)
        bfr[j] = *(const bf16x8*)(bs + (j * 16 + rl) * 64 + kc);
#pragma unroll
      for (int i = 0; i < 4; ++i)
#pragma unroll
        for (int j = 0; j < 4; ++j)
          acc[i][j] = __builtin_amdgcn_mfma_f32_16x16x32_bf16(af[i], bfr[j], acc[i][j], 0, 0, 0);
    }
  }

  // epilogue: C/D layout col=lane&15, row=(lane>>4)*4+r. Plain bf16 partials.
  int cl = lane & 15, rg = (lane >> 4) * 4;
  bf16* Yp = khalf ? Y1 : Y0;
#pragma unroll
  for (int i = 0; i < 4; ++i) {
    int ob = wr + i * 16 + rg;
#pragma unroll
    for (int j = 0; j < 4; ++j) {
      int nn = n0 + j * 16 + cl;
#pragma unroll
      for (int r = 0; r < 4; ++r) {
        float yv = acc[i][j][r] + (khalf ? 0.f : bias[ob + r]);
        Yp[(size_t)(ob + r) * NTOT + nn] = __float2bfloat16(yv);
      }
    }
  }
}

// ---------- 6. cooperative fused GN stats + apply ----------
// 1024 blocks x 256 thr; block (b,o) = (bid>>8, bid&255) owns one 4096-row.
// Each thread holds 16 y-values in registers; stats -> atomics -> grid sync
// -> normalize from registers -> coalesced f32 writes.
__global__ __launch_bounds__(256) void k_gnapply(const bf16* __restrict__ Y0,
                                                 const bf16* __restrict__ Y1,
                                                 const float* __restrict__ gamma,
                                                 const float* __restrict__ beta,
                                                 float* gsum, float* gsq,
                                                 float* __restrict__ out) {
  int bid = blockIdx.x;
  int tid = threadIdx.x;
  int o = bid & 255, b = bid >> 8;
  int g = o >> 3;
  size_t off = (size_t)o * NTOT + b * HW + tid * 16;
  bf16x8 a0 = *(const bf16x8*)(Y0 + off);
  bf16x8 a1 = *(const bf16x8*)(Y1 + off);
  bf16x8 b0 = *(const bf16x8*)(Y0 + off + 8);
  bf16x8 b1 = *(const bf16x8*)(Y1 + off + 8);
  float y[16];
#pragma unroll
  for (int k = 0; k < 8; ++k) y[k] = (float)a0[k] + (float)a1[k];
#pragma unroll
  for (int k = 0; k < 8; ++k) y[k + 8] = (float)b0[k] + (float)b1[k];
  float s = 0.f, s2 = 0.f;
#pragma unroll
  for (int k = 0; k < 16; ++k) {
    s += y[k];
    s2 = fmaf(y[k], y[k], s2);
  }
  int lane = tid & 63, wv = tid >> 6;
#pragma unroll
  for (int mk = 1; mk <= 32; mk <<= 1) {
    s += __shfl_xor(s, mk);
    s2 += __shfl_xor(s2, mk);
  }
  __shared__ float red[8];
  if (lane == 0) { red[wv] = s; red[wv + 4] = s2; }
  __syncthreads();
  if (tid == 0) {
    atomicAdd(&gsum[b * 32 + g], red[0] + red[1] + red[2] + red[3]);
    atomicAdd(&gsq[b * 32 + g], red[4] + red[5] + red[6] + red[7]);
  }
  __threadfence();
  cg::this_grid().sync();
  volatile float* vs = gsum;
  volatile float* vq = gsq;
  float mu = vs[b * 32 + g] * (1.f / 32768.f);
  float var = vq[b * 32 + g] * (1.f / 32768.f) - mu * mu;
  float rs = rsqrtf(var + 1e-5f);
  float sc = rs * gamma[o];
  float sh = beta[o] - mu * sc;
  float* op = out + ((size_t)b * COUT + o) * HW + tid * 16;
#pragma unroll
  for (int q = 0; q < 4; ++q) {
    f32x4 r;
#pragma unroll
    for (int k = 0; k < 4; ++k) r[k] = fmaxf(y[q * 4 + k] * sc + sh, 0.f);
    *(f32x4*)(op + q * 4) = r;
  }
}

extern "C" void kernel_launch(void* const* d_in, const int* in_sizes, int n_in,
                              void* d_out, int out_size, void* d_ws, size_t ws_size,
                              hipStream_t stream) {
  const float* x = (const float*)d_in[0];
  const float* w_off = (const float*)d_in[1];
  const float* b_off = (const float*)d_in[2];
  const float* w = (const float*)d_in[3];
  const float* bias = (const float*)d_in[4];
  const float* gamma = (const float*)d_in[5];
  const float* beta = (const float*)d_in[6];
  float* out = (float*)d_out;
  char* ws = (char*)d_ws;

  bf16* xt = (bf16*)(ws);                              //  8,388,608 B
  float* offb = (float*)(ws + 8388608);                //  1,179,648 B
  bf16* Abf = (bf16*)(ws + 8388608 + 1179648);         //  1,179,648 B
  bf16* colsT = (bf16*)(ws + 8388608 + 2 * 1179648);   // 75,497,472 B
  bf16* Y0 = (bf16*)(ws + 8388608 + 2 * 1179648 + 75497472);   // 8,388,608 B
  bf16* Y1 = Y0 + (size_t)COUT * NTOT;                         // 8,388,608 B
  float* gsum = (float*)(ws + 3 * 8388608 + 2 * 1179648 + 75497472);
  float* gsq = gsum + 128;

  // scratch for the offset conv, aliased into the colsT region (dead until
  // k_gather, which runs after k_offreduce and fully overwrites it)
  float* wt = (float*)colsT;                       // 165,888 B
  float* part = (float*)((char*)colsT + 262144);   // 9,437,184 B

  k_pre<<<4515, 256, 0, stream>>>(x, w, w_off, xt, Abf, wt, gsum);
  k_convoff2<<<512, 256, 0, stream>>>(x, wt, part);
  k_offreduce<<<288, 256, 0, stream>>>(part, b_off, offb);
  k_gather<<<4096, 256, 0, stream>>>(xt, offb, colsT);
  k_gemm<<<512, 256, 0, stream>>>(Abf, colsT, bias, Y0, Y1);

  const bf16* cY0 = Y0;
  const bf16* cY1 = Y1;
  void* args[] = {(void*)&cY0, (void*)&cY1, (void*)&gamma, (void*)&beta,
                  (void*)&gsum, (void*)&gsq, (void*)&out};
  hipLaunchCooperativeKernel((const void*)k_gnapply, dim3(1024), dim3(256),
                             args, 0, stream);
}

// Round 17
// 128.886 us; speedup vs baseline: 2.4782x; 2.4782x over previous
//
#include <hip/hip_runtime.h>
#include <hip/hip_bf16.h>

using bf16 = __hip_bfloat16;
typedef __attribute__((ext_vector_type(4))) float f32x4;
typedef __attribute__((ext_vector_type(2))) float f32x2;
typedef __attribute__((ext_vector_type(8))) __bf16 bf16x8;
typedef __attribute__((ext_vector_type(4))) __bf16 bf16x4;

#define CIN 256
#define COUT 256
#define HW 4096
#define NB 4
#define NTOT 16384   // NB*HW
#define KDIM 2304    // CIN*9

// ---------- 1. merged pre-pass ----------
// blocks    0..2047: transpose x NCHW f32 -> xt NHWC bf16 (64c x 32hw tiles)
// blocks 2048..4351: w[o][c][p] f32 -> A[o][p*256+c] bf16
// blocks 4352..4513: wof[oc][c][p] -> wt[c][p][oc]
__global__ __launch_bounds__(256) void k_pre(const float* __restrict__ x,
                                             const float* __restrict__ w,
                                             const float* __restrict__ wof,
                                             bf16* __restrict__ xt,
                                             bf16* __restrict__ A,
                                             float* __restrict__ wt) {
  int bid = blockIdx.x;
  int tid = threadIdx.x;
  if (bid < 2048) {
    __shared__ float t[64][33];
    int ct = bid & 3;
    int hwt = (bid >> 2) & 127;
    int b = bid >> 9;
    int c0 = ct * 64, hw0 = hwt * 32;
    const float* xb = x + (size_t)b * CIN * HW;
    int cc = tid >> 5, ww = tid & 31;
#pragma unroll
    for (int pass = 0; pass < 8; ++pass)
      t[cc + pass * 8][ww] = xb[(size_t)(c0 + cc + pass * 8) * HW + hw0 + ww];
    __syncthreads();
    int hwl = tid >> 3, ce = (tid & 7) * 8;
    bf16x8 v;
#pragma unroll
    for (int e = 0; e < 8; ++e) v[e] = (__bf16)t[ce + e][hwl];
    *(bf16x8*)(xt + ((size_t)b * HW + hw0 + hwl) * CIN + c0 + ce) = v;
  } else if (bid < 4352) {
    int i = (bid - 2048) * 256 + tid;  // o*2304 + p*256 + c
    int o = i / KDIM, r = i % KDIM;
    int p = r >> 8, c = r & 255;
    A[i] = __float2bfloat16(w[((size_t)o * 256 + c) * 9 + p]);
  } else {
    int i = (bid - 4352) * 256 + tid;  // (c*9+p)*18 + oc
    if (i < 18 * CIN * 9) {
      int oc = i % 18;
      int cp = i / 18;
      int c = cp / 9, p = cp % 9;
      wt[i] = wof[((size_t)oc * CIN + c) * 9 + p];
    }
  }
}

// ---------- 2. offset conv partials: LDS-tiled, channel-chunked ----------
__global__ __launch_bounds__(256) void k_convoff2(const float* __restrict__ x,
                                                  const float* __restrict__ wt,
                                                  float* __restrict__ part) {
  __shared__ float lds[8][6][68];
  int bid = blockIdx.x;
  int chunk = bid & 7;
  int rt = (bid >> 3) & 15;
  int b = bid >> 7;
  int tid = threadIdx.x;
  int wq = tid & 63, r = tid >> 6;
  int h0 = rt * 4;
  int c0 = chunk * 32;

  if (tid < 96) {
    int cl = tid / 12, rem = tid % 12;
    lds[cl][rem >> 1][(rem & 1) ? 66 : 1] = 0.f;
  }

  float acc[18];
#pragma unroll
  for (int o = 0; o < 18; ++o) acc[o] = 0.f;

  int ch = tid >> 5, l32 = tid & 31;
  const float* xb = x + (size_t)b * CIN * HW;

  for (int cs = 0; cs < 32; cs += 8) {
    __syncthreads();
    const float* xp = xb + (size_t)(c0 + cs + ch) * HW;
#pragma unroll
    for (int r6 = 0; r6 < 6; ++r6) {
      int hh = h0 - 1 + r6;
      f32x2 v = {0.f, 0.f};
      if ((unsigned)hh < 64u) v = *(const f32x2*)(xp + hh * 64 + l32 * 2);
      *(f32x2*)&lds[ch][r6][2 + l32 * 2] = v;
    }
    __syncthreads();
#pragma unroll
    for (int cl = 0; cl < 8; ++cl) {
      int c = c0 + cs + cl;
      const float* wc = wt + (size_t)c * 9 * 18;
      float xv[9];
#pragma unroll
      for (int ky = 0; ky < 3; ++ky)
#pragma unroll
        for (int kx = 0; kx < 3; ++kx)
          xv[ky * 3 + kx] = lds[cl][r + ky][1 + wq + kx];
#pragma unroll
      for (int p = 0; p < 9; ++p)
#pragma unroll
        for (int o = 0; o < 18; ++o)
          acc[o] = fmaf(xv[p], wc[p * 18 + o], acc[o]);
    }
  }

  float* pp = part + (size_t)chunk * (NB * 18 * HW) + (size_t)b * 18 * HW +
              (h0 + r) * 64 + wq;
#pragma unroll
  for (int o = 0; o < 18; ++o) pp[(size_t)o * HW] = acc[o];
}

// ---------- 3. reduce channel-chunk partials + bias -> off[b][18][hw] ----------
__global__ __launch_bounds__(256) void k_offreduce(const float* __restrict__ part,
                                                   const float* __restrict__ boff,
                                                   float* __restrict__ off) {
  int i = blockIdx.x * 256 + threadIdx.x;
  int e0 = i * 4;
  int oc = (e0 >> 12) % 18;
  float bo = boff[oc];
  f32x4 s = {bo, bo, bo, bo};
#pragma unroll
  for (int c = 0; c < 8; ++c) s += *(const f32x4*)(part + (size_t)c * (NB * 18 * HW) + e0);
  *(f32x4*)(off + e0) = s;
}

// ---------- 4. bilinear gather (bf16 corners) -> colsT[n][p*256+c] ----------
__global__ __launch_bounds__(256) void k_gather(const bf16* __restrict__ xt,
                                                const float* __restrict__ off,
                                                bf16* __restrict__ colsT) {
  int tid = threadIdx.x;
  int wv = tid >> 6, l = tid & 63;
  int n = blockIdx.x * 4 + wv;
  int hw = n & 4095;
  int b = n >> 12;
  int h = hw >> 6, wq = hw & 63;
  const bf16* xtb = xt + (size_t)b * HW * CIN + l * 4;
  const float* offb = off + (size_t)b * 18 * HW + hw;
  bf16* outp = colsT + (size_t)n * KDIM + l * 4;
#pragma unroll
  for (int p = 0; p < 9; ++p) {
    float dy = offb[(size_t)(2 * p) * HW];
    float dx = offb[(size_t)(2 * p + 1) * HW];
    float ysf = (float)(h - 1 + p / 3) + dy;
    float xsf = (float)(wq - 1 + p % 3) + dx;
    float y0f = floorf(ysf), x0f = floorf(xsf);
    float wy1 = ysf - y0f, wx1 = xsf - x0f;
    float wy0 = 1.f - wy1, wx0 = 1.f - wx1;
    int y0 = (int)y0f, x0 = (int)x0f;
    int y1 = y0 + 1, x1 = x0 + 1;
    float w00 = wy0 * wx0, w01 = wy0 * wx1, w10 = wy1 * wx0, w11 = wy1 * wx1;
    bool vy0 = (unsigned)y0 < 64u, vy1 = (unsigned)y1 < 64u;
    bool vx0 = (unsigned)x0 < 64u, vx1 = (unsigned)x1 < 64u;
    w00 = (vy0 && vx0) ? w00 : 0.f;
    w01 = (vy0 && vx1) ? w01 : 0.f;
    w10 = (vy1 && vx0) ? w10 : 0.f;
    w11 = (vy1 && vx1) ? w11 : 0.f;
    int y0c = min(max(y0, 0), 63), y1c = min(max(y1, 0), 63);
    int x0c = min(max(x0, 0), 63), x1c = min(max(x1, 0), 63);
    bf16x4 c00 = *(const bf16x4*)(xtb + (size_t)(y0c * 64 + x0c) * CIN);
    bf16x4 c01 = *(const bf16x4*)(xtb + (size_t)(y0c * 64 + x1c) * CIN);
    bf16x4 c10 = *(const bf16x4*)(xtb + (size_t)(y1c * 64 + x0c) * CIN);
    bf16x4 c11 = *(const bf16x4*)(xtb + (size_t)(y1c * 64 + x1c) * CIN);
    bf16x4 o;
#pragma unroll
    for (int k = 0; k < 4; ++k) {
      float v = w00 * (float)c00[k] + w01 * (float)c01[k] +
                w10 * (float)c10[k] + w11 * (float)c11[k];
      o[k] = (__bf16)v;
    }
    *(bf16x4*)(outp + p * 256) = o;
  }
}

// ---------- 5. split-K GEMM: BM=256, BN=64, K halved; 512 blocks (2/CU) ----------
__global__ __launch_bounds__(256) void k_gemm(const bf16* __restrict__ A,
                                              const bf16* __restrict__ Bt,
                                              const float* __restrict__ bias,
                                              bf16* __restrict__ Y0,
                                              bf16* __restrict__ Y1) {
  __shared__ bf16 As[2][256 * 64];  // 32 KB each
  __shared__ bf16 Bs[2][64 * 64];   //  8 KB each -> 80 KB total
  int bid = blockIdx.x;
  // bijective XCD swizzle over 512 blocks; pair (n-tile, khalf) stays on XCD
  int swz = (bid & 7) * 64 + (bid >> 3);
  int n0 = (swz >> 1) * 64;
  int khalf = swz & 1;
  int tid = threadIdx.x;
  int lane = tid & 63;
  int wave = tid >> 6;
  int wr = wave * 64;               // per-wave 64x64 output tile
  f32x4 acc[4][4];
#pragma unroll
  for (int i = 0; i < 4; ++i)
#pragma unroll
    for (int j = 0; j < 4; ++j) acc[i][j] = (f32x4){0.f, 0.f, 0.f, 0.f};

  int srow = tid >> 3;                              // 0..31
  int skdst = (tid & 7) * 8;                        // linear dest k-chunk
  int sksrc = ((tid & 7) ^ ((tid >> 3) & 7)) * 8;   // pre-swizzled source (T2)
  int kbase = khalf * 18;                           // K-step offset
  auto stage = [&](int buf, int kt) {               // 10 loads/thread
    int k0 = (kbase + kt) * 64;
#pragma unroll
    for (int ps = 0; ps < 8; ++ps) {
      int r = srow + ps * 32;
      __builtin_amdgcn_global_load_lds(
          (const __attribute__((address_space(1))) void*)(A + (size_t)r * KDIM + k0 + sksrc),
          (__attribute__((address_space(3))) void*)(&As[buf][r * 64 + skdst]), 16, 0, 0);
    }
#pragma unroll
    for (int ps = 0; ps < 2; ++ps) {
      int r = srow + ps * 32;
      __builtin_amdgcn_global_load_lds(
          (const __attribute__((address_space(1))) void*)(Bt + (size_t)(n0 + r) * KDIM + k0 + sksrc),
          (__attribute__((address_space(3))) void*)(&Bs[buf][r * 64 + skdst]), 16, 0, 0);
    }
  };

  stage(0, 0);
  int rl = lane & 15;
  int kb = (lane >> 4) * 8;
  int xorv = (rl & 7) * 8;  // read-side XOR (row&7)*8 elements; row&7 == rl&7
  for (int kt = 0; kt < 18; ++kt) {
    __syncthreads();  // drains vmcnt -> buf[kt&1] ready; all prev reads done
    if (kt + 1 < 18) stage((kt + 1) & 1, kt + 1);
    const bf16* as = As[kt & 1];
    const bf16* bs = Bs[kt & 1];
#pragma unroll
    for (int kh = 0; kh < 2; ++kh) {
      int kc = (kh * 32 + kb) ^ xorv;
      bf16x8 af[4], bfr[4];
#pragma unroll
      for (int i = 0; i < 4; ++i)
        af[i] = *(const bf16x8*)(as + (wr + i * 16 + rl) * 64 + kc);
#pragma unroll
      for (int j = 0; j < 4; ++j)
        bfr[j] = *(const bf16x8*)(bs + (j * 16 + rl) * 64 + kc);
#pragma unroll
      for (int i = 0; i < 4; ++i)
#pragma unroll
        for (int j = 0; j < 4; ++j)
          acc[i][j] = __builtin_amdgcn_mfma_f32_16x16x32_bf16(af[i], bfr[j], acc[i][j], 0, 0, 0);
    }
  }

  // epilogue: C/D layout col=lane&15, row=(lane>>4)*4+r. Plain bf16 partials.
  int cl = lane & 15, rg = (lane >> 4) * 4;
  bf16* Yp = khalf ? Y1 : Y0;
#pragma unroll
  for (int i = 0; i < 4; ++i) {
    int ob = wr + i * 16 + rg;
#pragma unroll
    for (int j = 0; j < 4; ++j) {
      int nn = n0 + j * 16 + cl;
#pragma unroll
      for (int r = 0; r < 4; ++r) {
        float yv = acc[i][j][r] + (khalf ? 0.f : bias[ob + r]);
        Yp[(size_t)(ob + r) * NTOT + nn] = __float2bfloat16(yv);
      }
    }
  }
}

// ---------- 6. fused GN stats + apply (block-local, no atomics) ----------
// 128 blocks x 1024 thr; block (b,g) owns its whole group: 8 ch x 4096 pos.
// thread: ch = tid>>7, pos = (tid&127)*32. y kept in registers between the
// stats reduce and the apply.
__global__ __launch_bounds__(1024) void k_gnapply(const bf16* __restrict__ Y0,
                                                  const bf16* __restrict__ Y1,
                                                  const float* __restrict__ gamma,
                                                  const float* __restrict__ beta,
                                                  float* __restrict__ out) {
  int bid = blockIdx.x;
  int b = bid >> 5, g = bid & 31;
  int tid = threadIdx.x;
  int ch = tid >> 7;
  int pos = (tid & 127) * 32;
  int o = g * 8 + ch;
  size_t off = (size_t)o * NTOT + b * HW + pos;
  float y[32];
#pragma unroll
  for (int q = 0; q < 4; ++q) {
    bf16x8 v0 = *(const bf16x8*)(Y0 + off + q * 8);
    bf16x8 v1 = *(const bf16x8*)(Y1 + off + q * 8);
#pragma unroll
    for (int k = 0; k < 8; ++k) y[q * 8 + k] = (float)v0[k] + (float)v1[k];
  }
  float s = 0.f, s2 = 0.f;
#pragma unroll
  for (int k = 0; k < 32; ++k) {
    s += y[k];
    s2 = fmaf(y[k], y[k], s2);
  }
  int lane = tid & 63, wv = tid >> 6;  // 16 waves
#pragma unroll
  for (int mk = 1; mk <= 32; mk <<= 1) {
    s += __shfl_xor(s, mk);
    s2 += __shfl_xor(s2, mk);
  }
  __shared__ float red[32];
  __shared__ float stats[2];
  if (lane == 0) { red[wv] = s; red[wv + 16] = s2; }
  __syncthreads();
  if (tid == 0) {
    float S = 0.f, S2 = 0.f;
#pragma unroll
    for (int k = 0; k < 16; ++k) {
      S += red[k];
      S2 += red[k + 16];
    }
    float mu = S * (1.f / 32768.f);
    float var = S2 * (1.f / 32768.f) - mu * mu;
    stats[0] = mu;
    stats[1] = rsqrtf(var + 1e-5f);
  }
  __syncthreads();
  float mu = stats[0], rs = stats[1];
  float sc = rs * gamma[o];
  float sh = beta[o] - mu * sc;
  float* op = out + ((size_t)b * COUT + o) * HW + pos;
#pragma unroll
  for (int q = 0; q < 8; ++q) {
    f32x4 r;
#pragma unroll
    for (int k = 0; k < 4; ++k) r[k] = fmaxf(y[q * 4 + k] * sc + sh, 0.f);
    *(f32x4*)(op + q * 4) = r;
  }
}

extern "C" void kernel_launch(void* const* d_in, const int* in_sizes, int n_in,
                              void* d_out, int out_size, void* d_ws, size_t ws_size,
                              hipStream_t stream) {
  const float* x = (const float*)d_in[0];
  const float* w_off = (const float*)d_in[1];
  const float* b_off = (const float*)d_in[2];
  const float* w = (const float*)d_in[3];
  const float* bias = (const float*)d_in[4];
  const float* gamma = (const float*)d_in[5];
  const float* beta = (const float*)d_in[6];
  float* out = (float*)d_out;
  char* ws = (char*)d_ws;

  bf16* xt = (bf16*)(ws);                              //  8,388,608 B
  float* offb = (float*)(ws + 8388608);                //  1,179,648 B
  bf16* Abf = (bf16*)(ws + 8388608 + 1179648);         //  1,179,648 B
  bf16* colsT = (bf16*)(ws + 8388608 + 2 * 1179648);   // 75,497,472 B
  bf16* Y0 = (bf16*)(ws + 8388608 + 2 * 1179648 + 75497472);   // 8,388,608 B
  bf16* Y1 = Y0 + (size_t)COUT * NTOT;                         // 8,388,608 B

  // scratch for the offset conv, aliased into the colsT region (dead until
  // k_gather, which runs after k_offreduce and fully overwrites it)
  float* wt = (float*)colsT;                       // 165,888 B
  float* part = (float*)((char*)colsT + 262144);   // 9,437,184 B

  k_pre<<<4514, 256, 0, stream>>>(x, w, w_off, xt, Abf, wt);
  k_convoff2<<<512, 256, 0, stream>>>(x, wt, part);
  k_offreduce<<<288, 256, 0, stream>>>(part, b_off, offb);
  k_gather<<<4096, 256, 0, stream>>>(xt, offb, colsT);
  k_gemm<<<512, 256, 0, stream>>>(Abf, colsT, bias, Y0, Y1);
  k_gnapply<<<128, 1024, 0, stream>>>(Y0, Y1, gamma, beta, out);
}

// Round 19
// 116.979 us; speedup vs baseline: 2.7305x; 1.1018x over previous
//
#include <hip/hip_runtime.h>
#include <hip/hip_bf16.h>

using bf16 = __hip_bfloat16;
typedef __attribute__((ext_vector_type(4))) float f32x4;
typedef __attribute__((ext_vector_type(2))) float f32x2;
typedef __attribute__((ext_vector_type(8))) __bf16 bf16x8;
typedef __attribute__((ext_vector_type(4))) __bf16 bf16x4;

#define CIN 256
#define COUT 256
#define HW 4096
#define NB 4
#define NTOT 16384   // NB*HW
#define KDIM 2304    // CIN*9

// ---------- 1. merged pre-pass ----------
__global__ __launch_bounds__(256) void k_pre(const float* __restrict__ x,
                                             const float* __restrict__ w,
                                             const float* __restrict__ wof,
                                             bf16* __restrict__ xt,
                                             bf16* __restrict__ A,
                                             float* __restrict__ wt) {
  int bid = blockIdx.x;
  int tid = threadIdx.x;
  if (bid < 2048) {
    __shared__ float t[64][33];
    int ct = bid & 3;
    int hwt = (bid >> 2) & 127;
    int b = bid >> 9;
    int c0 = ct * 64, hw0 = hwt * 32;
    const float* xb = x + (size_t)b * CIN * HW;
    int cc = tid >> 5, ww = tid & 31;
#pragma unroll
    for (int pass = 0; pass < 8; ++pass)
      t[cc + pass * 8][ww] = xb[(size_t)(c0 + cc + pass * 8) * HW + hw0 + ww];
    __syncthreads();
    int hwl = tid >> 3, ce = (tid & 7) * 8;
    bf16x8 v;
#pragma unroll
    for (int e = 0; e < 8; ++e) v[e] = (__bf16)t[ce + e][hwl];
    *(bf16x8*)(xt + ((size_t)b * HW + hw0 + hwl) * CIN + c0 + ce) = v;
  } else if (bid < 4352) {
    int i = (bid - 2048) * 256 + tid;  // o*2304 + p*256 + c
    int o = i / KDIM, r = i % KDIM;
    int p = r >> 8, c = r & 255;
    A[i] = __float2bfloat16(w[((size_t)o * 256 + c) * 9 + p]);
  } else {
    int i = (bid - 4352) * 256 + tid;  // (c*9+p)*18 + oc
    if (i < 18 * CIN * 9) {
      int oc = i % 18;
      int cp = i / 18;
      int c = cp / 9, p = cp % 9;
      wt[i] = wof[((size_t)oc * CIN + c) * 9 + p];
    }
  }
}

// ---------- 2. offset conv partials: LDS-tiled, channel-chunked ----------
__global__ __launch_bounds__(256) void k_convoff2(const float* __restrict__ x,
                                                  const float* __restrict__ wt,
                                                  float* __restrict__ part) {
  __shared__ float lds[8][6][68];
  int bid = blockIdx.x;
  int chunk = bid & 7;
  int rt = (bid >> 3) & 15;
  int b = bid >> 7;
  int tid = threadIdx.x;
  int wq = tid & 63, r = tid >> 6;
  int h0 = rt * 4;
  int c0 = chunk * 32;

  if (tid < 96) {
    int cl = tid / 12, rem = tid % 12;
    lds[cl][rem >> 1][(rem & 1) ? 66 : 1] = 0.f;
  }

  float acc[18];
#pragma unroll
  for (int o = 0; o < 18; ++o) acc[o] = 0.f;

  int ch = tid >> 5, l32 = tid & 31;
  const float* xb = x + (size_t)b * CIN * HW;

  for (int cs = 0; cs < 32; cs += 8) {
    __syncthreads();
    const float* xp = xb + (size_t)(c0 + cs + ch) * HW;
#pragma unroll
    for (int r6 = 0; r6 < 6; ++r6) {
      int hh = h0 - 1 + r6;
      f32x2 v = {0.f, 0.f};
      if ((unsigned)hh < 64u) v = *(const f32x2*)(xp + hh * 64 + l32 * 2);
      *(f32x2*)&lds[ch][r6][2 + l32 * 2] = v;
    }
    __syncthreads();
#pragma unroll
    for (int cl = 0; cl < 8; ++cl) {
      int c = c0 + cs + cl;
      const float* wc = wt + (size_t)c * 9 * 18;
      float xv[9];
#pragma unroll
      for (int ky = 0; ky < 3; ++ky)
#pragma unroll
        for (int kx = 0; kx < 3; ++kx)
          xv[ky * 3 + kx] = lds[cl][r + ky][1 + wq + kx];
#pragma unroll
      for (int p = 0; p < 9; ++p)
#pragma unroll
        for (int o = 0; o < 18; ++o)
          acc[o] = fmaf(xv[p], wc[p * 18 + o], acc[o]);
    }
  }

  float* pp = part + (size_t)chunk * (NB * 18 * HW) + (size_t)b * 18 * HW +
              (h0 + r) * 64 + wq;
#pragma unroll
  for (int o = 0; o < 18; ++o) pp[(size_t)o * HW] = acc[o];
}

// ---------- 3. reduce channel-chunk partials + bias -> off[b][18][hw] ----------
__global__ __launch_bounds__(256) void k_offreduce(const float* __restrict__ part,
                                                   const float* __restrict__ boff,
                                                   float* __restrict__ off) {
  int i = blockIdx.x * 256 + threadIdx.x;
  int e0 = i * 4;
  int oc = (e0 >> 12) % 18;
  float bo = boff[oc];
  f32x4 s = {bo, bo, bo, bo};
#pragma unroll
  for (int c = 0; c < 8; ++c) s += *(const f32x4*)(part + (size_t)c * (NB * 18 * HW) + e0);
  *(f32x4*)(off + e0) = s;
}

// ---------- 4. bilinear gather (bf16 corners) -> colsT[n][p*256+c] ----------
__global__ __launch_bounds__(256) void k_gather(const bf16* __restrict__ xt,
                                                const float* __restrict__ off,
                                                bf16* __restrict__ colsT) {
  int tid = threadIdx.x;
  int wv = tid >> 6, l = tid & 63;
  int n = blockIdx.x * 4 + wv;
  int hw = n & 4095;
  int b = n >> 12;
  int h = hw >> 6, wq = hw & 63;
  const bf16* xtb = xt + (size_t)b * HW * CIN + l * 4;
  const float* offb = off + (size_t)b * 18 * HW + hw;
  bf16* outp = colsT + (size_t)n * KDIM + l * 4;
#pragma unroll
  for (int p = 0; p < 9; ++p) {
    float dy = offb[(size_t)(2 * p) * HW];
    float dx = offb[(size_t)(2 * p + 1) * HW];
    float ysf = (float)(h - 1 + p / 3) + dy;
    float xsf = (float)(wq - 1 + p % 3) + dx;
    float y0f = floorf(ysf), x0f = floorf(xsf);
    float wy1 = ysf - y0f, wx1 = xsf - x0f;
    float wy0 = 1.f - wy1, wx0 = 1.f - wx1;
    int y0 = (int)y0f, x0 = (int)x0f;
    int y1 = y0 + 1, x1 = x0 + 1;
    float w00 = wy0 * wx0, w01 = wy0 * wx1, w10 = wy1 * wx0, w11 = wy1 * wx1;
    bool vy0 = (unsigned)y0 < 64u, vy1 = (unsigned)y1 < 64u;
    bool vx0 = (unsigned)x0 < 64u, vx1 = (unsigned)x1 < 64u;
    w00 = (vy0 && vx0) ? w00 : 0.f;
    w01 = (vy0 && vx1) ? w01 : 0.f;
    w10 = (vy1 && vx0) ? w10 : 0.f;
    w11 = (vy1 && vx1) ? w11 : 0.f;
    int y0c = min(max(y0, 0), 63), y1c = min(max(y1, 0), 63);
    int x0c = min(max(x0, 0), 63), x1c = min(max(x1, 0), 63);
    bf16x4 c00 = *(const bf16x4*)(xtb + (size_t)(y0c * 64 + x0c) * CIN);
    bf16x4 c01 = *(const bf16x4*)(xtb + (size_t)(y0c * 64 + x1c) * CIN);
    bf16x4 c10 = *(const bf16x4*)(xtb + (size_t)(y1c * 64 + x0c) * CIN);
    bf16x4 c11 = *(const bf16x4*)(xtb + (size_t)(y1c * 64 + x1c) * CIN);
    bf16x4 o;
#pragma unroll
    for (int k = 0; k < 4; ++k) {
      float v = w00 * (float)c00[k] + w01 * (float)c01[k] +
                w10 * (float)c10[k] + w11 * (float)c11[k];
      o[k] = (__bf16)v;
    }
    *(bf16x4*)(outp + p * 256) = o;
  }
}

// ---------- 5. split-K GEMM, 8 waves: BM=256, BN=64; 512 blocks (2/CU) ----------
// 512 threads = 8 waves, per-wave 64x32 tile -> 16 waves/CU (4/SIMD).
// Depth-1 syncthreads-dbuf (R15-proven): stage kt+1 into buf (kt+1)&1 after
// the barrier; __syncthreads drains vmcnt so buf kt&1 is complete when read.
__global__ __launch_bounds__(512) void k_gemm(const bf16* __restrict__ A,
                                              const bf16* __restrict__ Bt,
                                              const float* __restrict__ bias,
                                              bf16* __restrict__ Y0,
                                              bf16* __restrict__ Y1) {
  __shared__ bf16 As[2][256 * 64];  // 32 KB each
  __shared__ bf16 Bs[2][64 * 64];   //  8 KB each -> 80 KB total
  int bid = blockIdx.x;
  // bijective XCD swizzle over 512 blocks; pair (n-tile, khalf) stays on XCD
  int swz = (bid & 7) * 64 + (bid >> 3);
  int n0 = (swz >> 1) * 64;
  int khalf = swz & 1;
  int tid = threadIdx.x;
  int lane = tid & 63;
  int wave = tid >> 6;                       // 0..7
  int wr = (wave >> 1) * 64;                 // row base (0/64/128/192)
  int wc = (wave & 1) * 32;                  // col base (0/32)
  f32x4 acc[4][2];
#pragma unroll
  for (int i = 0; i < 4; ++i)
#pragma unroll
    for (int j = 0; j < 2; ++j) acc[i][j] = (f32x4){0.f, 0.f, 0.f, 0.f};

  int srow = tid >> 3;                              // 0..63
  int skdst = (tid & 7) * 8;                        // linear dest k-chunk
  int sksrc = ((tid & 7) ^ ((tid >> 3) & 7)) * 8;   // pre-swizzled source (T2)
  int kbase = khalf * 18;                           // K-step offset
  auto stage = [&](int buf, int kt) {               // 5 loads/thread
    int k0 = (kbase + kt) * 64;
#pragma unroll
    for (int ps = 0; ps < 4; ++ps) {
      int r = srow + ps * 64;
      __builtin_amdgcn_global_load_lds(
          (const __attribute__((address_space(1))) void*)(A + (size_t)r * KDIM + k0 + sksrc),
          (__attribute__((address_space(3))) void*)(&As[buf][r * 64 + skdst]), 16, 0, 0);
    }
    __builtin_amdgcn_global_load_lds(
        (const __attribute__((address_space(1))) void*)(Bt + (size_t)(n0 + srow) * KDIM + k0 + sksrc),
        (__attribute__((address_space(3))) void*)(&Bs[buf][srow * 64 + skdst]), 16, 0, 0);
  };

  stage(0, 0);
  int rl = lane & 15;
  int kb = (lane >> 4) * 8;
  int xorv = (rl & 7) * 8;  // read-side XOR (row&7)*8 elements; row&7 == rl&7
  for (int kt = 0; kt < 18; ++kt) {
    __syncthreads();  // drains vmcnt -> buf[kt&1] ready; all prev reads done
    if (kt + 1 < 18) stage((kt + 1) & 1, kt + 1);
    const bf16* as = As[kt & 1];
    const bf16* bs = Bs[kt & 1];
#pragma unroll
    for (int kh = 0; kh < 2; ++kh) {
      int kc = (kh * 32 + kb) ^ xorv;
      bf16x8 af[4], bfr[2];
#pragma unroll
      for (int i = 0; i < 4; ++i)
        af[i] = *(const bf16x8*)(as + (wr + i * 16 + rl) * 64 + kc);
#pragma unroll
      for (int j = 0; j < 2; ++j)
        bfr[j] = *(const bf16x8*)(bs + (wc + j * 16 + rl) * 64 + kc);
#pragma unroll
      for (int i = 0; i < 4; ++i)
#pragma unroll
        for (int j = 0; j < 2; ++j)
          acc[i][j] = __builtin_amdgcn_mfma_f32_16x16x32_bf16(af[i], bfr[j], acc[i][j], 0, 0, 0);
    }
  }

  // epilogue: C/D layout col=lane&15, row=(lane>>4)*4+r. Plain bf16 partials.
  int cl = lane & 15, rg = (lane >> 4) * 4;
  bf16* Yp = khalf ? Y1 : Y0;
#pragma unroll
  for (int i = 0; i < 4; ++i) {
    int ob = wr + i * 16 + rg;
#pragma unroll
    for (int j = 0; j < 2; ++j) {
      int nn = n0 + wc + j * 16 + cl;
#pragma unroll
      for (int r = 0; r < 4; ++r) {
        float yv = acc[i][j][r] + (khalf ? 0.f : bias[ob + r]);
        Yp[(size_t)(ob + r) * NTOT + nn] = __float2bfloat16(yv);
      }
    }
  }
}

// ---------- 6. fused GN stats + apply (block-local, no atomics) ----------
__global__ __launch_bounds__(1024) void k_gnapply(const bf16* __restrict__ Y0,
                                                  const bf16* __restrict__ Y1,
                                                  const float* __restrict__ gamma,
                                                  const float* __restrict__ beta,
                                                  float* __restrict__ out) {
  int bid = blockIdx.x;
  int b = bid >> 5, g = bid & 31;
  int tid = threadIdx.x;
  int ch = tid >> 7;
  int pos = (tid & 127) * 32;
  int o = g * 8 + ch;
  size_t off = (size_t)o * NTOT + b * HW + pos;
  float y[32];
#pragma unroll
  for (int q = 0; q < 4; ++q) {
    bf16x8 v0 = *(const bf16x8*)(Y0 + off + q * 8);
    bf16x8 v1 = *(const bf16x8*)(Y1 + off + q * 8);
#pragma unroll
    for (int k = 0; k < 8; ++k) y[q * 8 + k] = (float)v0[k] + (float)v1[k];
  }
  float s = 0.f, s2 = 0.f;
#pragma unroll
  for (int k = 0; k < 32; ++k) {
    s += y[k];
    s2 = fmaf(y[k], y[k], s2);
  }
  int lane = tid & 63, wv = tid >> 6;  // 16 waves
#pragma unroll
  for (int mk = 1; mk <= 32; mk <<= 1) {
    s += __shfl_xor(s, mk);
    s2 += __shfl_xor(s2, mk);
  }
  __shared__ float red[32];
  __shared__ float stats[2];
  if (lane == 0) { red[wv] = s; red[wv + 16] = s2; }
  __syncthreads();
  if (tid == 0) {
    float S = 0.f, S2 = 0.f;
#pragma unroll
    for (int k = 0; k < 16; ++k) {
      S += red[k];
      S2 += red[k + 16];
    }
    float mu = S * (1.f / 32768.f);
    float var = S2 * (1.f / 32768.f) - mu * mu;
    stats[0] = mu;
    stats[1] = rsqrtf(var + 1e-5f);
  }
  __syncthreads();
  float mu = stats[0], rs = stats[1];
  float sc = rs * gamma[o];
  float sh = beta[o] - mu * sc;
  float* op = out + ((size_t)b * COUT + o) * HW + pos;
#pragma unroll
  for (int q = 0; q < 8; ++q) {
    f32x4 r;
#pragma unroll
    for (int k = 0; k < 4; ++k) r[k] = fmaxf(y[q * 4 + k] * sc + sh, 0.f);
    *(f32x4*)(op + q * 4) = r;
  }
}

extern "C" void kernel_launch(void* const* d_in, const int* in_sizes, int n_in,
                              void* d_out, int out_size, void* d_ws, size_t ws_size,
                              hipStream_t stream) {
  const float* x = (const float*)d_in[0];
  const float* w_off = (const float*)d_in[1];
  const float* b_off = (const float*)d_in[2];
  const float* w = (const float*)d_in[3];
  const float* bias = (const float*)d_in[4];
  const float* gamma = (const float*)d_in[5];
  const float* beta = (const float*)d_in[6];
  float* out = (float*)d_out;
  char* ws = (char*)d_ws;

  bf16* xt = (bf16*)(ws);                              //  8,388,608 B
  float* offb = (float*)(ws + 8388608);                //  1,179,648 B
  bf16* Abf = (bf16*)(ws + 8388608 + 1179648);         //  1,179,648 B
  bf16* colsT = (bf16*)(ws + 8388608 + 2 * 1179648);   // 75,497,472 B
  bf16* Y0 = (bf16*)(ws + 8388608 + 2 * 1179648 + 75497472);   // 8,388,608 B
  bf16* Y1 = Y0 + (size_t)COUT * NTOT;                         // 8,388,608 B

  // scratch for the offset conv, aliased into the colsT region (dead until
  // k_gather, which runs after k_offreduce and fully overwrites it)
  float* wt = (float*)colsT;                       // 165,888 B
  float* part = (float*)((char*)colsT + 262144);   // 9,437,184 B

  k_pre<<<4514, 256, 0, stream>>>(x, w, w_off, xt, Abf, wt);
  k_convoff2<<<512, 256, 0, stream>>>(x, wt, part);
  k_offreduce<<<288, 256, 0, stream>>>(part, b_off, offb);
  k_gather<<<4096, 256, 0, stream>>>(xt, offb, colsT);
  k_gemm<<<512, 512, 0, stream>>>(Abf, colsT, bias, Y0, Y1);
  k_gnapply<<<128, 1024, 0, stream>>>(Y0, Y1, gamma, beta, out);
}